// Round 1
// baseline (460.446 us; speedup 1.0000x reference)
//
#include <hip/hip_runtime.h>

// N=4, Cin=512, C=D=256, S=H*W=16384
// prep   : split coarse -> q hi/lo bf16 | fold BN into w1 -> hi/lo      (movement, 134 MB)
// conv   : k = relu(BN(conv1)) NT-MFMA 3-pass; A=w1 hi/lo, B = feat fp32 staged into LDS
//          via width-16 global_load_lds (bit4-XOR swizzled source), column-gather + cheap
//          RNE split -> frags.  Output k hi/lo bf16.
// energy : E_part[32 splits] = q.k^T NT-MFMA 3-pass, partial stores (K=512 per split)
// softmax: att = softmax(-sum Ep) over c  (max-shift cancels)
// m2h    : M2[o,d] = w2 @ att^T -> bf16
// final  : out = M2 @ q + b2; same staging as conv, hi-only B build, fp32 out
// LDS layouts:
//   A tiles: [k-octet 4][row 128][8] u16 -> wave w stages octet w (linear gld16 dest);
//            fragment ds_read_b128 is 16B/lane sequential (no bank conflicts).
//   B fp32 tile: linear [32][128] with col ^= ((row>>3)&1)<<4 swizzle, applied on the
//            global SOURCE address (gld_lds dest must stay linear) and on the read index.
//            Column-gather banks: 2 quads per 16-bank half = 2-way = free (m136).
// Numerics identical to previous version: RNE hi + RNE lo everywhere (absmax preserved).

#define S_DIM 16384
#define C_DIM 256
#define CIN 512

typedef unsigned short u16;
typedef __attribute__((ext_vector_type(8))) short bf16x8;
typedef __attribute__((ext_vector_type(4))) float f32x4;

__device__ __forceinline__ u16 f2bf(float x) {
    unsigned u = __float_as_uint(x);
    u += 0x7fff + ((u >> 16) & 1);
    return (u16)(u >> 16);
}
__device__ __forceinline__ float bf2f(u16 h) {
    return __uint_as_float(((unsigned)h) << 16);
}
__device__ __forceinline__ void gld16(const u16* g, u16* l) {
    __builtin_amdgcn_global_load_lds((const __attribute__((address_space(1))) void*)g,
                                     (__attribute__((address_space(3))) void*)l, 16, 0, 0);
}
__device__ __forceinline__ void gld16f(const float* g, float* l) {
    __builtin_amdgcn_global_load_lds((const __attribute__((address_space(1))) void*)g,
                                     (__attribute__((address_space(3))) void*)l, 16, 0, 0);
}

// ================= prep: split coarse -> q hi/lo | fold w1 =================
__global__ __launch_bounds__(256) void prep_kernel(
    const float* __restrict__ coarse, const float* __restrict__ w1,
    const float* __restrict__ gamma, const float* __restrict__ beta,
    const float* __restrict__ mean, const float* __restrict__ var,
    u16* __restrict__ qhi, u16* __restrict__ qlo,
    u16* __restrict__ w1hi, u16* __restrict__ w1lo, float* __restrict__ b1) {
    int b = blockIdx.x;
    int t = threadIdx.x;
    if (b < 4096) {
        size_t i = (size_t)b * 256 + t;
        for (size_t c = i; c < 4194304u; c += 1048576u) {
            float4 v = ((const float4*)coarse)[c];
            float vv[4] = {v.x, v.y, v.z, v.w};
            u16 h[4], l[4];
#pragma unroll
            for (int j = 0; j < 4; ++j) {
                h[j] = f2bf(vv[j]);
                l[j] = f2bf(vv[j] - bf2f(h[j]));
            }
            *(uint2*)&qhi[c * 4] = *(uint2*)h;
            *(uint2*)&qlo[c * 4] = *(uint2*)l;
        }
    } else {
        int o = (b - 4096) * 16 + (t >> 4);
        int lane16 = t & 15;
        float sc = gamma[o] * rsqrtf(var[o] + 1e-5f);
        for (int i = lane16; i < CIN; i += 16) {
            float v = w1[o * CIN + i] * sc;
            u16 h = f2bf(v);
            w1hi[o * CIN + i] = h;
            w1lo[o * CIN + i] = f2bf(v - bf2f(h));
        }
        if (lane16 == 0) b1[o] = beta[o] - mean[o] * sc;
    }
}

// ================= conv: k = relu(BN(w1 @ feat)), 3-pass hi/lo =================
__global__ __launch_bounds__(256) void conv_kernel(
    const u16* __restrict__ w1hi, const u16* __restrict__ w1lo,
    const float* __restrict__ feat, const float* __restrict__ b1,
    u16* __restrict__ khi, u16* __restrict__ klo) {
    __shared__ u16 AhS[4096], AlS[4096];
    __shared__ float BfS[4096];
    int s0 = blockIdx.x * 128;
    int m0 = blockIdx.y * 128;
    int bz = blockIdx.z;
    int tid = threadIdx.x, wave = tid >> 6, lane = tid & 63;
    int quad = lane >> 4, l15 = lane & 15;
    int wm = wave >> 1, wn = wave & 1;

    // A: wave stages k-octet `wave` for rows lane / 64+lane
    const u16* gAh0 = w1hi + (size_t)(m0 + lane) * CIN + wave * 8;
    const u16* gAh1 = w1hi + (size_t)(m0 + 64 + lane) * CIN + wave * 8;
    const u16* gAl0 = w1lo + (size_t)(m0 + lane) * CIN + wave * 8;
    const u16* gAl1 = w1lo + (size_t)(m0 + 64 + lane) * CIN + wave * 8;
    u16* dAh = AhS + wave * 1024;
    u16* dAl = AlS + wave * 1024;
    // B: wave stages rows 8w..8w+7; per gld16: 2 rows (half-wave each), source col
    // pre-swizzled by bit4 flip for odd k-octets
    int bcol = ((lane & 31) * 4) ^ ((wave & 1) << 4);
    const float* gB = feat + (size_t)bz * ((size_t)CIN * S_DIM)
                    + (size_t)(8 * wave + (lane >> 5)) * S_DIM + s0 + bcol;
    float* dB = BfS + wave * 1024;

    f32x4 zero = {0.f, 0.f, 0.f, 0.f};
    f32x4 acc[4][4];
#pragma unroll
    for (int i = 0; i < 4; ++i)
#pragma unroll
        for (int j = 0; j < 4; ++j) acc[i][j] = zero;

    for (int kb = 0; kb < CIN; kb += 32) {
        __syncthreads();
        gld16(gAh0 + kb, dAh);
        gld16(gAh1 + kb, dAh + 512);
        gld16(gAl0 + kb, dAl);
        gld16(gAl1 + kb, dAl + 512);
#pragma unroll
        for (int p = 0; p < 4; ++p)
            gld16f(gB + (size_t)(kb + 2 * p) * S_DIM, dB + p * 256);
        __syncthreads();

        bf16x8 a_h[4], a_l[4];
        int aOff = quad * 1024 + (wm * 64 + l15) * 8;
#pragma unroll
        for (int t = 0; t < 4; ++t) {
            a_h[t] = *(const bf16x8*)&AhS[aOff + t * 128];
            a_l[t] = *(const bf16x8*)&AlS[aOff + t * 128];
        }
        bf16x8 b_h[4], b_l[4];
        int fl = (quad & 1) << 4;
        const float* Brow = BfS + quad * 1024;  // rows quad*8..quad*8+7
#pragma unroll
        for (int nt = 0; nt < 4; ++nt) {
            int nf = (wn * 64 + nt * 16 + l15) ^ fl;
            union { unsigned d[4]; bf16x8 v; } H, L;
#pragma unroll
            for (int d = 0; d < 4; ++d) {
                float fa = Brow[(2 * d) * 128 + nf];
                float fb = Brow[(2 * d + 1) * 128 + nf];
                unsigned ua = __float_as_uint(fa), ub = __float_as_uint(fb);
                unsigned ra = ua + 0x7fffu + ((ua >> 16) & 1);
                unsigned rb = ub + 0x7fffu + ((ub >> 16) & 1);
                H.d[d] = __byte_perm(ra, rb, 0x7632);
                unsigned la = __float_as_uint(fa - __uint_as_float(ra & 0xffff0000u));
                unsigned lb = __float_as_uint(fb - __uint_as_float(rb & 0xffff0000u));
                la += 0x7fffu + ((la >> 16) & 1);
                lb += 0x7fffu + ((lb >> 16) & 1);
                L.d[d] = __byte_perm(la, lb, 0x7632);
            }
            b_h[nt] = H.v;
            b_l[nt] = L.v;
        }
#pragma unroll
        for (int mt = 0; mt < 4; ++mt)
#pragma unroll
            for (int nt = 0; nt < 4; ++nt) {
                acc[mt][nt] = __builtin_amdgcn_mfma_f32_16x16x32_bf16(a_h[mt], b_h[nt], acc[mt][nt], 0, 0, 0);
                acc[mt][nt] = __builtin_amdgcn_mfma_f32_16x16x32_bf16(a_h[mt], b_l[nt], acc[mt][nt], 0, 0, 0);
                acc[mt][nt] = __builtin_amdgcn_mfma_f32_16x16x32_bf16(a_l[mt], b_h[nt], acc[mt][nt], 0, 0, 0);
            }
    }

#pragma unroll
    for (int mt = 0; mt < 4; ++mt) {
#pragma unroll
        for (int r = 0; r < 4; ++r) {
            int row = m0 + wm * 64 + mt * 16 + quad * 4 + r;
            float bi = b1[row];
#pragma unroll
            for (int nt = 0; nt < 4; ++nt) {
                int cc = s0 + wn * 64 + nt * 16 + l15;
                float v = fmaxf(acc[mt][nt][r] + bi, 0.f);
                u16 h = f2bf(v);
                size_t o = (size_t)bz * 4194304 + (size_t)row * S_DIM + cc;
                khi[o] = h;
                klo[o] = f2bf(v - bf2f(h));
            }
        }
    }
}

// ================= energy: Ep[split] = q.k^T (3-pass hi/lo), 32 splits of K=512 =====
__global__ __launch_bounds__(256) void energy_kernel(
    const u16* __restrict__ qhi, const u16* __restrict__ qlo,
    const u16* __restrict__ khi, const u16* __restrict__ klo,
    float* __restrict__ Ep) {
    __shared__ u16 AhS[4096], BhS[4096], AlS[4096], BlS[4096];
    int kBeg = blockIdx.x * 512;
    int m0 = (blockIdx.y >> 1) * 128;
    int n0 = (blockIdx.y & 1) * 128;
    int bz = blockIdx.z;
    int tid = threadIdx.x, wave = tid >> 6, lane = tid & 63;
    int quad = lane >> 4, l15 = lane & 15;
    int wm = wave >> 1, wn = wave & 1;

    size_t bo = (size_t)bz * 4194304;
    const u16* gAh0 = qhi + bo + (size_t)(m0 + lane) * S_DIM + kBeg + wave * 8;
    const u16* gAh1 = qhi + bo + (size_t)(m0 + 64 + lane) * S_DIM + kBeg + wave * 8;
    const u16* gAl0 = qlo + bo + (size_t)(m0 + lane) * S_DIM + kBeg + wave * 8;
    const u16* gAl1 = qlo + bo + (size_t)(m0 + 64 + lane) * S_DIM + kBeg + wave * 8;
    const u16* gBh0 = khi + bo + (size_t)(n0 + lane) * S_DIM + kBeg + wave * 8;
    const u16* gBh1 = khi + bo + (size_t)(n0 + 64 + lane) * S_DIM + kBeg + wave * 8;
    const u16* gBl0 = klo + bo + (size_t)(n0 + lane) * S_DIM + kBeg + wave * 8;
    const u16* gBl1 = klo + bo + (size_t)(n0 + 64 + lane) * S_DIM + kBeg + wave * 8;
    u16* dAh = AhS + wave * 1024;
    u16* dAl = AlS + wave * 1024;
    u16* dBh = BhS + wave * 1024;
    u16* dBl = BlS + wave * 1024;

    f32x4 zero = {0.f, 0.f, 0.f, 0.f};
    f32x4 acc[4][4];
#pragma unroll
    for (int i = 0; i < 4; ++i)
#pragma unroll
        for (int j = 0; j < 4; ++j) acc[i][j] = zero;

    for (int kb = 0; kb < 512; kb += 32) {
        __syncthreads();
        gld16(gAh0 + kb, dAh);
        gld16(gAh1 + kb, dAh + 512);
        gld16(gBh0 + kb, dBh);
        gld16(gBh1 + kb, dBh + 512);
        gld16(gAl0 + kb, dAl);
        gld16(gAl1 + kb, dAl + 512);
        gld16(gBl0 + kb, dBl);
        gld16(gBl1 + kb, dBl + 512);
        __syncthreads();

        bf16x8 a_h[4], b_h[4], a_l[4], b_l[4];
        int aOff = quad * 1024 + (wm * 64 + l15) * 8;
        int bOff = quad * 1024 + (wn * 64 + l15) * 8;
#pragma unroll
        for (int t = 0; t < 4; ++t) {
            a_h[t] = *(const bf16x8*)&AhS[aOff + t * 128];
            b_h[t] = *(const bf16x8*)&BhS[bOff + t * 128];
            a_l[t] = *(const bf16x8*)&AlS[aOff + t * 128];
            b_l[t] = *(const bf16x8*)&BlS[bOff + t * 128];
        }
#pragma unroll
        for (int mt = 0; mt < 4; ++mt)
#pragma unroll
            for (int nt = 0; nt < 4; ++nt) {
                acc[mt][nt] = __builtin_amdgcn_mfma_f32_16x16x32_bf16(a_h[mt], b_h[nt], acc[mt][nt], 0, 0, 0);
                acc[mt][nt] = __builtin_amdgcn_mfma_f32_16x16x32_bf16(a_h[mt], b_l[nt], acc[mt][nt], 0, 0, 0);
                acc[mt][nt] = __builtin_amdgcn_mfma_f32_16x16x32_bf16(a_l[mt], b_h[nt], acc[mt][nt], 0, 0, 0);
            }
    }

    float* Ce = Ep + ((size_t)(blockIdx.x * 4 + bz)) * 65536;
#pragma unroll
    for (int mt = 0; mt < 4; ++mt)
#pragma unroll
        for (int r = 0; r < 4; ++r) {
            int row = m0 + wm * 64 + mt * 16 + quad * 4 + r;
#pragma unroll
            for (int nt = 0; nt < 4; ++nt) {
                int cc = n0 + wn * 64 + nt * 16 + l15;
                Ce[(size_t)row * C_DIM + cc] = acc[mt][nt][r];
            }
        }
}

// ================= softmax(-sum Ep) over c =================
__global__ __launch_bounds__(256) void softmax_kernel(const float* __restrict__ Ep,
                                                      float* __restrict__ att) {
    __shared__ float red[4], red2[4];
    int b = blockIdx.x;  // n*256+d
    int t = threadIdx.x;
    const float* p = Ep + (size_t)b * 256 + t;
    float v = 0.f;
#pragma unroll 8
    for (int s = 0; s < 32; ++s) v += p[(size_t)s * 262144];
    float m = v;
#pragma unroll
    for (int o = 32; o > 0; o >>= 1) m = fminf(m, __shfl_xor(m, o, 64));
    int lane = t & 63, wid = t >> 6;
    if (lane == 0) red[wid] = m;
    __syncthreads();
    m = fminf(fminf(red[0], red[1]), fminf(red[2], red[3]));
    float e = expf(m - v);
    float s = e;
#pragma unroll
    for (int o = 32; o > 0; o >>= 1) s += __shfl_xor(s, o, 64);
    if (lane == 0) red2[wid] = s;
    __syncthreads();
    s = red2[0] + red2[1] + red2[2] + red2[3];
    att[(size_t)b * 256 + t] = e / s;
}

// ================= M2h[n,o,d] = bf16( sum_c w2[o,c]*att[n,d,c] ) =================
__global__ __launch_bounds__(256) void m2h_kernel(const float* __restrict__ w2,
                                                  const float* __restrict__ att,
                                                  u16* __restrict__ M2h) {
    int t = blockIdx.x * 256 + threadIdx.x;
    int d = t & 255, o = (t >> 8) & 255, n = t >> 16;
    const float4* wr = (const float4*)(w2 + (size_t)o * C_DIM);
    const float4* ar = (const float4*)(att + ((size_t)n * C_DIM + d) * C_DIM);
    float s = 0.0f;
#pragma unroll 4
    for (int c4 = 0; c4 < 64; ++c4) {
        float4 w = wr[c4];
        float4 a = ar[c4];
        s += w.x * a.x + w.y * a.y + w.z * a.z + w.w * a.w;
    }
    M2h[((size_t)n * C_DIM + o) * C_DIM + d] = f2bf(s);
}

// ================= final: out = M2 @ q + b2 (1-pass) =================
__global__ __launch_bounds__(256) void final_kernel(
    const u16* __restrict__ M2h, const float* __restrict__ coarse,
    const float* __restrict__ b2, float* __restrict__ out) {
    __shared__ u16 AhS[4096];
    __shared__ float BfS[4096];
    int s0 = blockIdx.x * 128;
    int m0 = blockIdx.y * 128;
    int bz = blockIdx.z;
    int tid = threadIdx.x, wave = tid >> 6, lane = tid & 63;
    int quad = lane >> 4, l15 = lane & 15;
    int wm = wave >> 1, wn = wave & 1;

    const u16* gA0 = M2h + (size_t)bz * 65536 + (size_t)(m0 + lane) * C_DIM + wave * 8;
    const u16* gA1 = M2h + (size_t)bz * 65536 + (size_t)(m0 + 64 + lane) * C_DIM + wave * 8;
    u16* dA = AhS + wave * 1024;
    int bcol = ((lane & 31) * 4) ^ ((wave & 1) << 4);
    const float* gB = coarse + (size_t)bz * 4194304
                    + (size_t)(8 * wave + (lane >> 5)) * S_DIM + s0 + bcol;
    float* dB = BfS + wave * 1024;

    f32x4 zero = {0.f, 0.f, 0.f, 0.f};
    f32x4 acc[4][4];
#pragma unroll
    for (int i = 0; i < 4; ++i)
#pragma unroll
        for (int j = 0; j < 4; ++j) acc[i][j] = zero;

    for (int kb = 0; kb < C_DIM; kb += 32) {
        __syncthreads();
        gld16(gA0 + kb, dA);
        gld16(gA1 + kb, dA + 512);
#pragma unroll
        for (int p = 0; p < 4; ++p)
            gld16f(gB + (size_t)(kb + 2 * p) * S_DIM, dB + p * 256);
        __syncthreads();

        bf16x8 a_h[4];
        int aOff = quad * 1024 + (wm * 64 + l15) * 8;
#pragma unroll
        for (int t = 0; t < 4; ++t) a_h[t] = *(const bf16x8*)&AhS[aOff + t * 128];
        bf16x8 b_h[4];
        int fl = (quad & 1) << 4;
        const float* Brow = BfS + quad * 1024;
#pragma unroll
        for (int nt = 0; nt < 4; ++nt) {
            int nf = (wn * 64 + nt * 16 + l15) ^ fl;
            union { unsigned d[4]; bf16x8 v; } H;
#pragma unroll
            for (int d = 0; d < 4; ++d) {
                float fa = Brow[(2 * d) * 128 + nf];
                float fb = Brow[(2 * d + 1) * 128 + nf];
                unsigned ua = __float_as_uint(fa), ub = __float_as_uint(fb);
                unsigned ra = ua + 0x7fffu + ((ua >> 16) & 1);
                unsigned rb = ub + 0x7fffu + ((ub >> 16) & 1);
                H.d[d] = __byte_perm(ra, rb, 0x7632);
            }
            b_h[nt] = H.v;
        }
#pragma unroll
        for (int mt = 0; mt < 4; ++mt)
#pragma unroll
            for (int nt = 0; nt < 4; ++nt)
                acc[mt][nt] = __builtin_amdgcn_mfma_f32_16x16x32_bf16(a_h[mt], b_h[nt], acc[mt][nt], 0, 0, 0);
    }

#pragma unroll
    for (int mt = 0; mt < 4; ++mt)
#pragma unroll
        for (int r = 0; r < 4; ++r) {
            int row = m0 + wm * 64 + mt * 16 + quad * 4 + r;
            float bi = b2[row];
#pragma unroll
            for (int nt = 0; nt < 4; ++nt) {
                int cc = s0 + wn * 64 + nt * 16 + l15;
                out[(size_t)bz * 4194304 + (size_t)row * S_DIM + cc] = acc[mt][nt][r] + bi;
            }
        }
}

extern "C" void kernel_launch(void* const* d_in, const int* in_sizes, int n_in,
                              void* d_out, int out_size, void* d_ws, size_t ws_size,
                              hipStream_t stream) {
    const float* feat   = (const float*)d_in[0];
    const float* coarse = (const float*)d_in[1];
    const float* w1     = (const float*)d_in[2];
    const float* gamma  = (const float*)d_in[3];
    const float* beta   = (const float*)d_in[4];
    const float* mean   = (const float*)d_in[5];
    const float* var    = (const float*)d_in[6];
    const float* w2     = (const float*)d_in[7];
    const float* b2     = (const float*)d_in[8];
    float* out = (float*)d_out;

    char* base = (char*)d_ws;  // ~204 MB
    u16* qhi   = (u16*)(base);                   // [4][256][16384]
    u16* qlo   = (u16*)(base + 33554432);
    u16* khi   = (u16*)(base + 67108864);        // [4][256][16384]
    u16* klo   = (u16*)(base + 100663296);
    float* Ep  = (float*)(base + 134217728);     // [32][4][256][256] = 33.5 MB
    float* att = (float*)(base + 201326592);     // [4][256][256]
    u16* M2h   = (u16*)(base + 202375168);
    u16* w1hi  = (u16*)(base + 202899456);
    u16* w1lo  = (u16*)(base + 203161600);
    float* b1  = (float*)(base + 203423744);

    prep_kernel<<<4112, 256, 0, stream>>>(coarse, w1, gamma, beta, mean, var,
                                          qhi, qlo, w1hi, w1lo, b1);

    conv_kernel<<<dim3(128, 2, 4), 256, 0, stream>>>(w1hi, w1lo, feat, b1, khi, klo);

    energy_kernel<<<dim3(32, 4, 4), 256, 0, stream>>>(qhi, qlo, khi, klo, Ep);

    softmax_kernel<<<1024, 256, 0, stream>>>(Ep, att);

    m2h_kernel<<<1024, 256, 0, stream>>>(w2, att, M2h);

    final_kernel<<<dim3(128, 2, 4), 256, 0, stream>>>(M2h, coarse, b2, out);
}

// Round 2
// 428.593 us; speedup vs baseline: 1.0743x; 1.0743x over previous
//
#include <hip/hip_runtime.h>

// N=4, Cin=512, C=D=256, S=H*W=16384
// All low precision is FP16 (11-bit mantissa) instead of BF16:
// prep   : split coarse -> q hi/lo fp16 | fold BN into w1 -> fp16 hi/lo
// conv   : k = relu(BN(conv1)) NT-MFMA **2-pass** (A=w1 hi/lo pair, B=feat single fp16).
//          B staged fp32 into LDS (gld16 + bit4 source swizzle), column-gather + 1 cvt/elem.
//          Output k fp16 hi/lo.
// energy : E_part[32 splits] = q.k^T NT-MFMA 3-pass fp16 (drop ql*kl), partial stores
// softmax: att = softmax(-sum Ep) over c  (max-shift cancels)
// m2h    : M2[o,d] = w2 @ att^T -> fp16
// final  : out = M2 @ q + b2; A=M2h fp16 single, B=coarse fp32 -> single fp16 cvt
// LDS layouts:
//   fp16 tiles: [row 128][32 k] u16 with octet-XOR (stored[row][s] = logical[row][s^((row>>1)&3)]):
//     staging source = 64B-coalesced row chunks (4 lanes/row, octets permuted within 64B),
//     frag ds_read_b128 = 2-way banks (free).  gld_lds dest stays linear (rule #21).
//   B fp32 tile: [32][128] linear, col ^= ((k_oct&1)<<4) applied on global source and read.
// Precision: conv error ~ fp16-rounding of feat (2^-11 rel) ~= old bf16-pair k-storage error;
// energy fp16 3-pass ~1e-5; k/q stored as fp16 pairs (2^-22) — absmax expected ~0.03.

#define S_DIM 16384
#define C_DIM 256
#define CIN 512

typedef unsigned short u16;
typedef _Float16 f16;
typedef __attribute__((ext_vector_type(8))) _Float16 f16x8;
typedef __attribute__((ext_vector_type(4))) float f32x4;

__device__ __forceinline__ u16 f2h(float x) {
    f16 h = (f16)x;  // v_cvt_f16_f32, RNE
    return *(u16*)&h;
}
__device__ __forceinline__ float h2f(u16 u) {
    f16 h = *(f16*)&u;
    return (float)h;
}
__device__ __forceinline__ void gld16(const u16* g, u16* l) {
    __builtin_amdgcn_global_load_lds((const __attribute__((address_space(1))) void*)g,
                                     (__attribute__((address_space(3))) void*)l, 16, 0, 0);
}
__device__ __forceinline__ void gld16f(const float* g, float* l) {
    __builtin_amdgcn_global_load_lds((const __attribute__((address_space(1))) void*)g,
                                     (__attribute__((address_space(3))) void*)l, 16, 0, 0);
}

// ================= prep: split coarse -> q hi/lo fp16 | fold w1 =================
__global__ __launch_bounds__(256) void prep_kernel(
    const float* __restrict__ coarse, const float* __restrict__ w1,
    const float* __restrict__ gamma, const float* __restrict__ beta,
    const float* __restrict__ mean, const float* __restrict__ var,
    u16* __restrict__ qhi, u16* __restrict__ qlo,
    u16* __restrict__ w1hi, u16* __restrict__ w1lo, float* __restrict__ b1) {
    int b = blockIdx.x;
    int t = threadIdx.x;
    if (b < 4096) {
        size_t i = (size_t)b * 256 + t;
        for (size_t c = i; c < 4194304u; c += 1048576u) {
            float4 v = ((const float4*)coarse)[c];
            float vv[4] = {v.x, v.y, v.z, v.w};
            u16 h[4], l[4];
#pragma unroll
            for (int j = 0; j < 4; ++j) {
                h[j] = f2h(vv[j]);
                l[j] = f2h(vv[j] - h2f(h[j]));
            }
            *(uint2*)&qhi[c * 4] = *(uint2*)h;
            *(uint2*)&qlo[c * 4] = *(uint2*)l;
        }
    } else {
        int o = (b - 4096) * 16 + (t >> 4);
        int lane16 = t & 15;
        float sc = gamma[o] * rsqrtf(var[o] + 1e-5f);
        for (int i = lane16; i < CIN; i += 16) {
            float v = w1[o * CIN + i] * sc;
            u16 h = f2h(v);
            w1hi[o * CIN + i] = h;
            w1lo[o * CIN + i] = f2h(v - h2f(h));
        }
        if (lane16 == 0) b1[o] = beta[o] - mean[o] * sc;
    }
}

// ================= conv: k = relu(BN(w1 @ feat)), 2-pass fp16 =================
__global__ __launch_bounds__(256) void conv_kernel(
    const u16* __restrict__ w1hi, const u16* __restrict__ w1lo,
    const float* __restrict__ feat, const float* __restrict__ b1,
    u16* __restrict__ khi, u16* __restrict__ klo) {
    __shared__ u16 AhS[4096], AlS[4096];
    __shared__ float BfS[4096];
    int s0 = blockIdx.x * 128;
    int m0 = blockIdx.y * 128;
    int bz = blockIdx.z;
    int tid = threadIdx.x, wave = tid >> 6, lane = tid & 63;
    int quad = lane >> 4, l15 = lane & 15;
    int wm = wave >> 1, wn = wave & 1;

    // A staging: chunk c = wave*2+p covers rows c*16..c*16+15 (64B coalesced per row)
    int Lr = lane >> 2, Ls = lane & 3;
    int koff = (Ls ^ ((Lr >> 1) & 3)) * 8;  // octet-XOR on source (dest stays linear)
    const u16* gAh = w1hi + (size_t)(m0 + wave * 32 + Lr) * CIN + koff;
    const u16* gAl = w1lo + (size_t)(m0 + wave * 32 + Lr) * CIN + koff;
    u16* dAh = AhS + wave * 1024;
    u16* dAl = AlS + wave * 1024;

    // B staging: [32][128] fp32, bit4 source swizzle keyed on k-octet parity
    int bcol = ((lane & 31) * 4) ^ ((wave & 1) << 4);
    const float* gB = feat + (size_t)bz * ((size_t)CIN * S_DIM)
                    + (size_t)(8 * wave + (lane >> 5)) * S_DIM + s0 + bcol;
    float* dB = BfS + wave * 1024;

    f32x4 zero = {0.f, 0.f, 0.f, 0.f};
    f32x4 acc[4][4];
#pragma unroll
    for (int i = 0; i < 4; ++i)
#pragma unroll
        for (int j = 0; j < 4; ++j) acc[i][j] = zero;

    for (int kb = 0; kb < CIN; kb += 32) {
        __syncthreads();
        gld16(gAh + kb, dAh);
        gld16(gAh + kb + 16 * CIN, dAh + 512);
        gld16(gAl + kb, dAl);
        gld16(gAl + kb + 16 * CIN, dAl + 512);
#pragma unroll
        for (int p = 0; p < 4; ++p)
            gld16f(gB + (size_t)(kb + 2 * p) * S_DIM, dB + p * 256);
        __syncthreads();

        f16x8 a_h[4], a_l[4];
        int axor = ((l15 >> 1) & 3);  // (row>>1)&3 for row = wm*64+t*16+l15
        int ao = (wm * 64 + l15) * 32 + ((quad ^ axor) * 8);
#pragma unroll
        for (int t = 0; t < 4; ++t) {
            a_h[t] = *(const f16x8*)&AhS[ao + t * 512];
            a_l[t] = *(const f16x8*)&AlS[ao + t * 512];
        }
        f16x8 b_s[4];
        int fl = (quad & 1) << 4;
        const float* Brow = BfS + quad * 1024;  // k rows quad*8..quad*8+7
#pragma unroll
        for (int nt = 0; nt < 4; ++nt) {
            int nf = (wn * 64 + nt * 16 + l15) ^ fl;
            union { u16 u[8]; f16x8 v; } T;
#pragma unroll
            for (int j = 0; j < 8; ++j) T.u[j] = f2h(Brow[j * 128 + nf]);
            b_s[nt] = T.v;
        }
#pragma unroll
        for (int mt = 0; mt < 4; ++mt)
#pragma unroll
            for (int nt = 0; nt < 4; ++nt) {
                acc[mt][nt] = __builtin_amdgcn_mfma_f32_16x16x32_f16(a_h[mt], b_s[nt], acc[mt][nt], 0, 0, 0);
                acc[mt][nt] = __builtin_amdgcn_mfma_f32_16x16x32_f16(a_l[mt], b_s[nt], acc[mt][nt], 0, 0, 0);
            }
    }

#pragma unroll
    for (int mt = 0; mt < 4; ++mt) {
#pragma unroll
        for (int r = 0; r < 4; ++r) {
            int row = m0 + wm * 64 + mt * 16 + quad * 4 + r;
            float bi = b1[row];
#pragma unroll
            for (int nt = 0; nt < 4; ++nt) {
                int cc = s0 + wn * 64 + nt * 16 + l15;
                float v = fmaxf(acc[mt][nt][r] + bi, 0.f);
                u16 h = f2h(v);
                size_t o = (size_t)bz * 4194304 + (size_t)row * S_DIM + cc;
                khi[o] = h;
                klo[o] = f2h(v - h2f(h));
            }
        }
    }
}

// ================= energy: Ep[split] = q.k^T (3-pass fp16), 32 splits of K=512 =====
__global__ __launch_bounds__(256) void energy_kernel(
    const u16* __restrict__ qhi, const u16* __restrict__ qlo,
    const u16* __restrict__ khi, const u16* __restrict__ klo,
    float* __restrict__ Ep) {
    __shared__ u16 AhS[4096], BhS[4096], AlS[4096], BlS[4096];
    int kBeg = blockIdx.x * 512;
    int m0 = (blockIdx.y >> 1) * 128;
    int n0 = (blockIdx.y & 1) * 128;
    int bz = blockIdx.z;
    int tid = threadIdx.x, wave = tid >> 6, lane = tid & 63;
    int quad = lane >> 4, l15 = lane & 15;
    int wm = wave >> 1, wn = wave & 1;

    int Lr = lane >> 2, Ls = lane & 3;
    int koff = (Ls ^ ((Lr >> 1) & 3)) * 8;
    size_t bo = (size_t)bz * 4194304;
    const u16* gAh = qhi + bo + (size_t)(m0 + wave * 32 + Lr) * S_DIM + kBeg + koff;
    const u16* gAl = qlo + bo + (size_t)(m0 + wave * 32 + Lr) * S_DIM + kBeg + koff;
    const u16* gBh = khi + bo + (size_t)(n0 + wave * 32 + Lr) * S_DIM + kBeg + koff;
    const u16* gBl = klo + bo + (size_t)(n0 + wave * 32 + Lr) * S_DIM + kBeg + koff;
    u16* dAh = AhS + wave * 1024;
    u16* dAl = AlS + wave * 1024;
    u16* dBh = BhS + wave * 1024;
    u16* dBl = BlS + wave * 1024;

    f32x4 zero = {0.f, 0.f, 0.f, 0.f};
    f32x4 acc[4][4];
#pragma unroll
    for (int i = 0; i < 4; ++i)
#pragma unroll
        for (int j = 0; j < 4; ++j) acc[i][j] = zero;

    const size_t row16 = (size_t)16 * S_DIM;
    for (int kb = 0; kb < 512; kb += 32) {
        __syncthreads();
        gld16(gAh + kb, dAh);
        gld16(gAh + kb + row16, dAh + 512);
        gld16(gBh + kb, dBh);
        gld16(gBh + kb + row16, dBh + 512);
        gld16(gAl + kb, dAl);
        gld16(gAl + kb + row16, dAl + 512);
        gld16(gBl + kb, dBl);
        gld16(gBl + kb + row16, dBl + 512);
        __syncthreads();

        f16x8 a_h[4], b_h[4], a_l[4], b_l[4];
        int axor = ((l15 >> 1) & 3);
        int aOff = (wm * 64 + l15) * 32 + ((quad ^ axor) * 8);
        int bOff = (wn * 64 + l15) * 32 + ((quad ^ axor) * 8);
#pragma unroll
        for (int t = 0; t < 4; ++t) {
            a_h[t] = *(const f16x8*)&AhS[aOff + t * 512];
            b_h[t] = *(const f16x8*)&BhS[bOff + t * 512];
            a_l[t] = *(const f16x8*)&AlS[aOff + t * 512];
            b_l[t] = *(const f16x8*)&BlS[bOff + t * 512];
        }
#pragma unroll
        for (int mt = 0; mt < 4; ++mt)
#pragma unroll
            for (int nt = 0; nt < 4; ++nt) {
                acc[mt][nt] = __builtin_amdgcn_mfma_f32_16x16x32_f16(a_h[mt], b_h[nt], acc[mt][nt], 0, 0, 0);
                acc[mt][nt] = __builtin_amdgcn_mfma_f32_16x16x32_f16(a_h[mt], b_l[nt], acc[mt][nt], 0, 0, 0);
                acc[mt][nt] = __builtin_amdgcn_mfma_f32_16x16x32_f16(a_l[mt], b_h[nt], acc[mt][nt], 0, 0, 0);
            }
    }

    float* Ce = Ep + ((size_t)(blockIdx.x * 4 + bz)) * 65536;
#pragma unroll
    for (int mt = 0; mt < 4; ++mt)
#pragma unroll
        for (int r = 0; r < 4; ++r) {
            int row = m0 + wm * 64 + mt * 16 + quad * 4 + r;
#pragma unroll
            for (int nt = 0; nt < 4; ++nt) {
                int cc = n0 + wn * 64 + nt * 16 + l15;
                Ce[(size_t)row * C_DIM + cc] = acc[mt][nt][r];
            }
        }
}

// ================= softmax(-sum Ep) over c =================
__global__ __launch_bounds__(256) void softmax_kernel(const float* __restrict__ Ep,
                                                      float* __restrict__ att) {
    __shared__ float red[4], red2[4];
    int b = blockIdx.x;  // n*256+d
    int t = threadIdx.x;
    const float* p = Ep + (size_t)b * 256 + t;
    float v = 0.f;
#pragma unroll 8
    for (int s = 0; s < 32; ++s) v += p[(size_t)s * 262144];
    float m = v;
#pragma unroll
    for (int o = 32; o > 0; o >>= 1) m = fminf(m, __shfl_xor(m, o, 64));
    int lane = t & 63, wid = t >> 6;
    if (lane == 0) red[wid] = m;
    __syncthreads();
    m = fminf(fminf(red[0], red[1]), fminf(red[2], red[3]));
    float e = expf(m - v);
    float s = e;
#pragma unroll
    for (int o = 32; o > 0; o >>= 1) s += __shfl_xor(s, o, 64);
    if (lane == 0) red2[wid] = s;
    __syncthreads();
    s = red2[0] + red2[1] + red2[2] + red2[3];
    att[(size_t)b * 256 + t] = e / s;
}

// ================= M2h[n,o,d] = fp16( sum_c w2[o,c]*att[n,d,c] ) =================
__global__ __launch_bounds__(256) void m2h_kernel(const float* __restrict__ w2,
                                                  const float* __restrict__ att,
                                                  u16* __restrict__ M2h) {
    int t = blockIdx.x * 256 + threadIdx.x;
    int d = t & 255, o = (t >> 8) & 255, n = t >> 16;
    const float4* wr = (const float4*)(w2 + (size_t)o * C_DIM);
    const float4* ar = (const float4*)(att + ((size_t)n * C_DIM + d) * C_DIM);
    float s = 0.0f;
#pragma unroll 4
    for (int c4 = 0; c4 < 64; ++c4) {
        float4 w = wr[c4];
        float4 a = ar[c4];
        s += w.x * a.x + w.y * a.y + w.z * a.z + w.w * a.w;
    }
    M2h[((size_t)n * C_DIM + o) * C_DIM + d] = f2h(s);
}

// ================= final: out = M2 @ q + b2 (1-pass fp16) =================
__global__ __launch_bounds__(256) void final_kernel(
    const u16* __restrict__ M2h, const float* __restrict__ coarse,
    const float* __restrict__ b2, float* __restrict__ out) {
    __shared__ u16 AhS[4096];
    __shared__ float BfS[4096];
    int s0 = blockIdx.x * 128;
    int m0 = blockIdx.y * 128;
    int bz = blockIdx.z;
    int tid = threadIdx.x, wave = tid >> 6, lane = tid & 63;
    int quad = lane >> 4, l15 = lane & 15;
    int wm = wave >> 1, wn = wave & 1;

    int Lr = lane >> 2, Ls = lane & 3;
    int koff = (Ls ^ ((Lr >> 1) & 3)) * 8;
    const u16* gA = M2h + (size_t)bz * 65536 + (size_t)(m0 + wave * 32 + Lr) * C_DIM + koff;
    u16* dA = AhS + wave * 1024;
    int bcol = ((lane & 31) * 4) ^ ((wave & 1) << 4);
    const float* gB = coarse + (size_t)bz * 4194304
                    + (size_t)(8 * wave + (lane >> 5)) * S_DIM + s0 + bcol;
    float* dB = BfS + wave * 1024;

    f32x4 zero = {0.f, 0.f, 0.f, 0.f};
    f32x4 acc[4][4];
#pragma unroll
    for (int i = 0; i < 4; ++i)
#pragma unroll
        for (int j = 0; j < 4; ++j) acc[i][j] = zero;

    for (int kb = 0; kb < C_DIM; kb += 32) {
        __syncthreads();
        gld16(gA + kb, dA);
        gld16(gA + kb + 16 * C_DIM, dA + 512);
#pragma unroll
        for (int p = 0; p < 4; ++p)
            gld16f(gB + (size_t)(kb + 2 * p) * S_DIM, dB + p * 256);
        __syncthreads();

        f16x8 a_s[4];
        int axor = ((l15 >> 1) & 3);
        int ao = (wm * 64 + l15) * 32 + ((quad ^ axor) * 8);
#pragma unroll
        for (int t = 0; t < 4; ++t) a_s[t] = *(const f16x8*)&AhS[ao + t * 512];
        f16x8 b_s[4];
        int fl = (quad & 1) << 4;
        const float* Brow = BfS + quad * 1024;
#pragma unroll
        for (int nt = 0; nt < 4; ++nt) {
            int nf = (wn * 64 + nt * 16 + l15) ^ fl;
            union { u16 u[8]; f16x8 v; } T;
#pragma unroll
            for (int j = 0; j < 8; ++j) T.u[j] = f2h(Brow[j * 128 + nf]);
            b_s[nt] = T.v;
        }
#pragma unroll
        for (int mt = 0; mt < 4; ++mt)
#pragma unroll
            for (int nt = 0; nt < 4; ++nt)
                acc[mt][nt] = __builtin_amdgcn_mfma_f32_16x16x32_f16(a_s[mt], b_s[nt], acc[mt][nt], 0, 0, 0);
    }

#pragma unroll
    for (int mt = 0; mt < 4; ++mt)
#pragma unroll
        for (int r = 0; r < 4; ++r) {
            int row = m0 + wm * 64 + mt * 16 + quad * 4 + r;
            float bi = b2[row];
#pragma unroll
            for (int nt = 0; nt < 4; ++nt) {
                int cc = s0 + wn * 64 + nt * 16 + l15;
                out[(size_t)bz * 4194304 + (size_t)row * S_DIM + cc] = acc[mt][nt][r] + bi;
            }
        }
}

extern "C" void kernel_launch(void* const* d_in, const int* in_sizes, int n_in,
                              void* d_out, int out_size, void* d_ws, size_t ws_size,
                              hipStream_t stream) {
    const float* feat   = (const float*)d_in[0];
    const float* coarse = (const float*)d_in[1];
    const float* w1     = (const float*)d_in[2];
    const float* gamma  = (const float*)d_in[3];
    const float* beta   = (const float*)d_in[4];
    const float* mean   = (const float*)d_in[5];
    const float* var    = (const float*)d_in[6];
    const float* w2     = (const float*)d_in[7];
    const float* b2     = (const float*)d_in[8];
    float* out = (float*)d_out;

    char* base = (char*)d_ws;  // ~204 MB
    u16* qhi   = (u16*)(base);                   // [4][256][16384]
    u16* qlo   = (u16*)(base + 33554432);
    u16* khi   = (u16*)(base + 67108864);        // [4][256][16384]
    u16* klo   = (u16*)(base + 100663296);
    float* Ep  = (float*)(base + 134217728);     // [32][4][256][256] = 33.5 MB
    float* att = (float*)(base + 201326592);     // [4][256][256]
    u16* M2h   = (u16*)(base + 202375168);
    u16* w1hi  = (u16*)(base + 202899456);
    u16* w1lo  = (u16*)(base + 203161600);
    float* b1  = (float*)(base + 203423744);

    prep_kernel<<<4112, 256, 0, stream>>>(coarse, w1, gamma, beta, mean, var,
                                          qhi, qlo, w1hi, w1lo, b1);

    conv_kernel<<<dim3(128, 2, 4), 256, 0, stream>>>(w1hi, w1lo, feat, b1, khi, klo);

    energy_kernel<<<dim3(32, 4, 4), 256, 0, stream>>>(qhi, qlo, khi, klo, Ep);

    softmax_kernel<<<1024, 256, 0, stream>>>(Ep, att);

    m2h_kernel<<<1024, 256, 0, stream>>>(w2, att, M2h);

    final_kernel<<<dim3(128, 2, 4), 256, 0, stream>>>(M2h, coarse, b2, out);
}

// Round 3
// 423.109 us; speedup vs baseline: 1.0882x; 1.0130x over previous
//
#include <hip/hip_runtime.h>

// N=4, Cin=512, C=D=256, S=H*W=16384
// All low precision is FP16 (11-bit mantissa):
// prep   : split coarse -> q hi/lo fp16 | fold BN into w1 -> fp16 hi/lo
// conv   : k = relu(BN(conv1)) NT-MFMA 2-pass (A=w1 hi/lo pair, B=feat single fp16).
// energy : E_part[32 splits] = q.k^T NT-MFMA 3-pass fp16 (drop ql*kl), partial stores
// softmax: att = softmax(-sum Ep) over c  (max-shift cancels)
// m2h    : M2[o,d] = w2 @ att^T -> fp16
// final  : out = M2 @ q + b2; A=M2h fp16 single, B=coarse fp32 -> single fp16 cvt
//
// PIPELINE (this round): all three MFMA kernels use a 2-phase double-buffered
// K-loop — stage tile t+1 into buf^1 BEFORE computing tile t, ONE barrier per
// step (implicit vmcnt(0) drains the prefetch after it had the whole compute
// phase in flight).  Was: stage -> barrier -> compute -> barrier (zero overlap,
// latency-bound: MfmaUtil 15 / VALU 23 / HBM 20 / occ 20 all low).
//
// LDS layouts (unchanged):
//   fp16 tiles: [row 128][32 k] u16, octet-XOR stored[row][s]=logical[row][s^((row>>1)&3)]
//     staging source = 64B-coalesced row chunks; frag ds_read_b128 2-way banks (free).
//   B fp32 tile: [32][128] linear, col ^= ((k_oct&1)<<4) on global source and read.

#define S_DIM 16384
#define C_DIM 256
#define CIN 512

typedef unsigned short u16;
typedef _Float16 f16;
typedef __attribute__((ext_vector_type(8))) _Float16 f16x8;
typedef __attribute__((ext_vector_type(4))) float f32x4;

__device__ __forceinline__ u16 f2h(float x) {
    f16 h = (f16)x;  // v_cvt_f16_f32, RNE
    return *(u16*)&h;
}
__device__ __forceinline__ float h2f(u16 u) {
    f16 h = *(f16*)&u;
    return (float)h;
}
__device__ __forceinline__ void gld16(const u16* g, u16* l) {
    __builtin_amdgcn_global_load_lds((const __attribute__((address_space(1))) void*)g,
                                     (__attribute__((address_space(3))) void*)l, 16, 0, 0);
}
__device__ __forceinline__ void gld16f(const float* g, float* l) {
    __builtin_amdgcn_global_load_lds((const __attribute__((address_space(1))) void*)g,
                                     (__attribute__((address_space(3))) void*)l, 16, 0, 0);
}

// stage one [128 rows][32 k] u16 tile chunk pair (rows wave*32.. & +16) into LDS
__device__ __forceinline__ void stage_pair(const u16* g, int kb, size_t row16,
                                           u16* d, int wave) {
    gld16(g + kb, d + wave * 1024);
    gld16(g + kb + row16, d + wave * 1024 + 512);
}
// stage [32 k][128 s] fp32 tile (wave stages k rows 8w..8w+7)
__device__ __forceinline__ void stage_b(const float* g, int kb, float* d, int wave) {
#pragma unroll
    for (int p = 0; p < 4; ++p)
        gld16f(g + (size_t)(kb + 2 * p) * S_DIM, d + wave * 1024 + p * 256);
}

// ================= prep: split coarse -> q hi/lo fp16 | fold w1 =================
__global__ __launch_bounds__(256) void prep_kernel(
    const float* __restrict__ coarse, const float* __restrict__ w1,
    const float* __restrict__ gamma, const float* __restrict__ beta,
    const float* __restrict__ mean, const float* __restrict__ var,
    u16* __restrict__ qhi, u16* __restrict__ qlo,
    u16* __restrict__ w1hi, u16* __restrict__ w1lo, float* __restrict__ b1) {
    int b = blockIdx.x;
    int t = threadIdx.x;
    if (b < 4096) {
        size_t i = (size_t)b * 256 + t;
        for (size_t c = i; c < 4194304u; c += 1048576u) {
            float4 v = ((const float4*)coarse)[c];
            float vv[4] = {v.x, v.y, v.z, v.w};
            u16 h[4], l[4];
#pragma unroll
            for (int j = 0; j < 4; ++j) {
                h[j] = f2h(vv[j]);
                l[j] = f2h(vv[j] - h2f(h[j]));
            }
            *(uint2*)&qhi[c * 4] = *(uint2*)h;
            *(uint2*)&qlo[c * 4] = *(uint2*)l;
        }
    } else {
        int o = (b - 4096) * 16 + (t >> 4);
        int lane16 = t & 15;
        float sc = gamma[o] * rsqrtf(var[o] + 1e-5f);
        for (int i = lane16; i < CIN; i += 16) {
            float v = w1[o * CIN + i] * sc;
            u16 h = f2h(v);
            w1hi[o * CIN + i] = h;
            w1lo[o * CIN + i] = f2h(v - h2f(h));
        }
        if (lane16 == 0) b1[o] = beta[o] - mean[o] * sc;
    }
}

// ================= conv: k = relu(BN(w1 @ feat)), 2-pass fp16, 2-phase dbuf =====
__global__ __launch_bounds__(256) void conv_kernel(
    const u16* __restrict__ w1hi, const u16* __restrict__ w1lo,
    const float* __restrict__ feat, const float* __restrict__ b1,
    u16* __restrict__ khi, u16* __restrict__ klo) {
    __shared__ u16 AhS[2][4096], AlS[2][4096];
    __shared__ float BfS[2][4096];
    int s0 = blockIdx.x * 128;
    int m0 = blockIdx.y * 128;
    int bz = blockIdx.z;
    int tid = threadIdx.x, wave = tid >> 6, lane = tid & 63;
    int quad = lane >> 4, l15 = lane & 15;
    int wm = wave >> 1, wn = wave & 1;

    int Lr = lane >> 2, Ls = lane & 3;
    int koff = (Ls ^ ((Lr >> 1) & 3)) * 8;  // octet-XOR on source (dest stays linear)
    const u16* gAh = w1hi + (size_t)(m0 + wave * 32 + Lr) * CIN + koff;
    const u16* gAl = w1lo + (size_t)(m0 + wave * 32 + Lr) * CIN + koff;
    int bcol = ((lane & 31) * 4) ^ ((wave & 1) << 4);
    const float* gB = feat + (size_t)bz * ((size_t)CIN * S_DIM)
                    + (size_t)(8 * wave + (lane >> 5)) * S_DIM + s0 + bcol;

    f32x4 zero = {0.f, 0.f, 0.f, 0.f};
    f32x4 acc[4][4];
#pragma unroll
    for (int i = 0; i < 4; ++i)
#pragma unroll
        for (int j = 0; j < 4; ++j) acc[i][j] = zero;

    stage_pair(gAh, 0, 16 * CIN, AhS[0], wave);
    stage_pair(gAl, 0, 16 * CIN, AlS[0], wave);
    stage_b(gB, 0, BfS[0], wave);
    __syncthreads();

    int cur = 0;
    for (int kb = 0; kb < CIN; kb += 32) {
        if (kb + 32 < CIN) {
            stage_pair(gAh, kb + 32, 16 * CIN, AhS[cur ^ 1], wave);
            stage_pair(gAl, kb + 32, 16 * CIN, AlS[cur ^ 1], wave);
            stage_b(gB, kb + 32, BfS[cur ^ 1], wave);
        }

        f16x8 a_h[4], a_l[4];
        int axor = ((l15 >> 1) & 3);  // (row>>1)&3 for row = wm*64+t*16+l15
        int ao = (wm * 64 + l15) * 32 + ((quad ^ axor) * 8);
#pragma unroll
        for (int t = 0; t < 4; ++t) {
            a_h[t] = *(const f16x8*)&AhS[cur][ao + t * 512];
            a_l[t] = *(const f16x8*)&AlS[cur][ao + t * 512];
        }
        f16x8 b_s[4];
        int fl = (quad & 1) << 4;
        const float* Brow = BfS[cur] + quad * 1024;  // k rows quad*8..quad*8+7
#pragma unroll
        for (int nt = 0; nt < 4; ++nt) {
            int nf = (wn * 64 + nt * 16 + l15) ^ fl;
            union { u16 u[8]; f16x8 v; } T;
#pragma unroll
            for (int j = 0; j < 8; ++j) T.u[j] = f2h(Brow[j * 128 + nf]);
            b_s[nt] = T.v;
        }
#pragma unroll
        for (int mt = 0; mt < 4; ++mt)
#pragma unroll
            for (int nt = 0; nt < 4; ++nt) {
                acc[mt][nt] = __builtin_amdgcn_mfma_f32_16x16x32_f16(a_h[mt], b_s[nt], acc[mt][nt], 0, 0, 0);
                acc[mt][nt] = __builtin_amdgcn_mfma_f32_16x16x32_f16(a_l[mt], b_s[nt], acc[mt][nt], 0, 0, 0);
            }
        __syncthreads();
        cur ^= 1;
    }

#pragma unroll
    for (int mt = 0; mt < 4; ++mt) {
#pragma unroll
        for (int r = 0; r < 4; ++r) {
            int row = m0 + wm * 64 + mt * 16 + quad * 4 + r;
            float bi = b1[row];
#pragma unroll
            for (int nt = 0; nt < 4; ++nt) {
                int cc = s0 + wn * 64 + nt * 16 + l15;
                float v = fmaxf(acc[mt][nt][r] + bi, 0.f);
                u16 h = f2h(v);
                size_t o = (size_t)bz * 4194304 + (size_t)row * S_DIM + cc;
                khi[o] = h;
                klo[o] = f2h(v - h2f(h));
            }
        }
    }
}

// ===== energy: Ep[split] = q.k^T (3-pass fp16), 32 splits of K=512, 2-phase dbuf ===
__global__ __launch_bounds__(256) void energy_kernel(
    const u16* __restrict__ qhi, const u16* __restrict__ qlo,
    const u16* __restrict__ khi, const u16* __restrict__ klo,
    float* __restrict__ Ep) {
    __shared__ u16 AhS[2][4096], BhS[2][4096], AlS[2][4096], BlS[2][4096];
    int kBeg = blockIdx.x * 512;
    int m0 = (blockIdx.y >> 1) * 128;
    int n0 = (blockIdx.y & 1) * 128;
    int bz = blockIdx.z;
    int tid = threadIdx.x, wave = tid >> 6, lane = tid & 63;
    int quad = lane >> 4, l15 = lane & 15;
    int wm = wave >> 1, wn = wave & 1;

    int Lr = lane >> 2, Ls = lane & 3;
    int koff = (Ls ^ ((Lr >> 1) & 3)) * 8;
    size_t bo = (size_t)bz * 4194304;
    const u16* gAh = qhi + bo + (size_t)(m0 + wave * 32 + Lr) * S_DIM + kBeg + koff;
    const u16* gAl = qlo + bo + (size_t)(m0 + wave * 32 + Lr) * S_DIM + kBeg + koff;
    const u16* gBh = khi + bo + (size_t)(n0 + wave * 32 + Lr) * S_DIM + kBeg + koff;
    const u16* gBl = klo + bo + (size_t)(n0 + wave * 32 + Lr) * S_DIM + kBeg + koff;

    f32x4 zero = {0.f, 0.f, 0.f, 0.f};
    f32x4 acc[4][4];
#pragma unroll
    for (int i = 0; i < 4; ++i)
#pragma unroll
        for (int j = 0; j < 4; ++j) acc[i][j] = zero;

    const size_t row16 = (size_t)16 * S_DIM;
    stage_pair(gAh, 0, row16, AhS[0], wave);
    stage_pair(gBh, 0, row16, BhS[0], wave);
    stage_pair(gAl, 0, row16, AlS[0], wave);
    stage_pair(gBl, 0, row16, BlS[0], wave);
    __syncthreads();

    int cur = 0;
    for (int kb = 0; kb < 512; kb += 32) {
        if (kb + 32 < 512) {
            stage_pair(gAh, kb + 32, row16, AhS[cur ^ 1], wave);
            stage_pair(gBh, kb + 32, row16, BhS[cur ^ 1], wave);
            stage_pair(gAl, kb + 32, row16, AlS[cur ^ 1], wave);
            stage_pair(gBl, kb + 32, row16, BlS[cur ^ 1], wave);
        }

        f16x8 a_h[4], b_h[4], a_l[4], b_l[4];
        int axor = ((l15 >> 1) & 3);
        int aOff = (wm * 64 + l15) * 32 + ((quad ^ axor) * 8);
        int bOff = (wn * 64 + l15) * 32 + ((quad ^ axor) * 8);
#pragma unroll
        for (int t = 0; t < 4; ++t) {
            a_h[t] = *(const f16x8*)&AhS[cur][aOff + t * 512];
            b_h[t] = *(const f16x8*)&BhS[cur][bOff + t * 512];
            a_l[t] = *(const f16x8*)&AlS[cur][aOff + t * 512];
            b_l[t] = *(const f16x8*)&BlS[cur][bOff + t * 512];
        }
#pragma unroll
        for (int mt = 0; mt < 4; ++mt)
#pragma unroll
            for (int nt = 0; nt < 4; ++nt) {
                acc[mt][nt] = __builtin_amdgcn_mfma_f32_16x16x32_f16(a_h[mt], b_h[nt], acc[mt][nt], 0, 0, 0);
                acc[mt][nt] = __builtin_amdgcn_mfma_f32_16x16x32_f16(a_h[mt], b_l[nt], acc[mt][nt], 0, 0, 0);
                acc[mt][nt] = __builtin_amdgcn_mfma_f32_16x16x32_f16(a_l[mt], b_h[nt], acc[mt][nt], 0, 0, 0);
            }
        __syncthreads();
        cur ^= 1;
    }

    float* Ce = Ep + ((size_t)(blockIdx.x * 4 + bz)) * 65536;
#pragma unroll
    for (int mt = 0; mt < 4; ++mt)
#pragma unroll
        for (int r = 0; r < 4; ++r) {
            int row = m0 + wm * 64 + mt * 16 + quad * 4 + r;
#pragma unroll
            for (int nt = 0; nt < 4; ++nt) {
                int cc = n0 + wn * 64 + nt * 16 + l15;
                Ce[(size_t)row * C_DIM + cc] = acc[mt][nt][r];
            }
        }
}

// ================= softmax(-sum Ep) over c =================
__global__ __launch_bounds__(256) void softmax_kernel(const float* __restrict__ Ep,
                                                      float* __restrict__ att) {
    __shared__ float red[4], red2[4];
    int b = blockIdx.x;  // n*256+d
    int t = threadIdx.x;
    const float* p = Ep + (size_t)b * 256 + t;
    float v = 0.f;
#pragma unroll 8
    for (int s = 0; s < 32; ++s) v += p[(size_t)s * 262144];
    float m = v;
#pragma unroll
    for (int o = 32; o > 0; o >>= 1) m = fminf(m, __shfl_xor(m, o, 64));
    int lane = t & 63, wid = t >> 6;
    if (lane == 0) red[wid] = m;
    __syncthreads();
    m = fminf(fminf(red[0], red[1]), fminf(red[2], red[3]));
    float e = expf(m - v);
    float s = e;
#pragma unroll
    for (int o = 32; o > 0; o >>= 1) s += __shfl_xor(s, o, 64);
    if (lane == 0) red2[wid] = s;
    __syncthreads();
    s = red2[0] + red2[1] + red2[2] + red2[3];
    att[(size_t)b * 256 + t] = e / s;
}

// ================= M2h[n,o,d] = fp16( sum_c w2[o,c]*att[n,d,c] ) =================
__global__ __launch_bounds__(256) void m2h_kernel(const float* __restrict__ w2,
                                                  const float* __restrict__ att,
                                                  u16* __restrict__ M2h) {
    int t = blockIdx.x * 256 + threadIdx.x;
    int d = t & 255, o = (t >> 8) & 255, n = t >> 16;
    const float4* wr = (const float4*)(w2 + (size_t)o * C_DIM);
    const float4* ar = (const float4*)(att + ((size_t)n * C_DIM + d) * C_DIM);
    float s = 0.0f;
#pragma unroll 4
    for (int c4 = 0; c4 < 64; ++c4) {
        float4 w = wr[c4];
        float4 a = ar[c4];
        s += w.x * a.x + w.y * a.y + w.z * a.z + w.w * a.w;
    }
    M2h[((size_t)n * C_DIM + o) * C_DIM + d] = f2h(s);
}

// ================= final: out = M2 @ q + b2 (1-pass fp16, 2-phase dbuf) ==========
__global__ __launch_bounds__(256) void final_kernel(
    const u16* __restrict__ M2h, const float* __restrict__ coarse,
    const float* __restrict__ b2, float* __restrict__ out) {
    __shared__ u16 AhS[2][4096];
    __shared__ float BfS[2][4096];
    int s0 = blockIdx.x * 128;
    int m0 = blockIdx.y * 128;
    int bz = blockIdx.z;
    int tid = threadIdx.x, wave = tid >> 6, lane = tid & 63;
    int quad = lane >> 4, l15 = lane & 15;
    int wm = wave >> 1, wn = wave & 1;

    int Lr = lane >> 2, Ls = lane & 3;
    int koff = (Ls ^ ((Lr >> 1) & 3)) * 8;
    const u16* gA = M2h + (size_t)bz * 65536 + (size_t)(m0 + wave * 32 + Lr) * C_DIM + koff;
    int bcol = ((lane & 31) * 4) ^ ((wave & 1) << 4);
    const float* gB = coarse + (size_t)bz * 4194304
                    + (size_t)(8 * wave + (lane >> 5)) * S_DIM + s0 + bcol;

    f32x4 zero = {0.f, 0.f, 0.f, 0.f};
    f32x4 acc[4][4];
#pragma unroll
    for (int i = 0; i < 4; ++i)
#pragma unroll
        for (int j = 0; j < 4; ++j) acc[i][j] = zero;

    stage_pair(gA, 0, 16 * C_DIM, AhS[0], wave);
    stage_b(gB, 0, BfS[0], wave);
    __syncthreads();

    int cur = 0;
    for (int kb = 0; kb < C_DIM; kb += 32) {
        if (kb + 32 < C_DIM) {
            stage_pair(gA, kb + 32, 16 * C_DIM, AhS[cur ^ 1], wave);
            stage_b(gB, kb + 32, BfS[cur ^ 1], wave);
        }

        f16x8 a_s[4];
        int axor = ((l15 >> 1) & 3);
        int ao = (wm * 64 + l15) * 32 + ((quad ^ axor) * 8);
#pragma unroll
        for (int t = 0; t < 4; ++t) a_s[t] = *(const f16x8*)&AhS[cur][ao + t * 512];
        f16x8 b_s[4];
        int fl = (quad & 1) << 4;
        const float* Brow = BfS[cur] + quad * 1024;
#pragma unroll
        for (int nt = 0; nt < 4; ++nt) {
            int nf = (wn * 64 + nt * 16 + l15) ^ fl;
            union { u16 u[8]; f16x8 v; } T;
#pragma unroll
            for (int j = 0; j < 8; ++j) T.u[j] = f2h(Brow[j * 128 + nf]);
            b_s[nt] = T.v;
        }
#pragma unroll
        for (int mt = 0; mt < 4; ++mt)
#pragma unroll
            for (int nt = 0; nt < 4; ++nt)
                acc[mt][nt] = __builtin_amdgcn_mfma_f32_16x16x32_f16(a_s[mt], b_s[nt], acc[mt][nt], 0, 0, 0);
        __syncthreads();
        cur ^= 1;
    }

#pragma unroll
    for (int mt = 0; mt < 4; ++mt)
#pragma unroll
        for (int r = 0; r < 4; ++r) {
            int row = m0 + wm * 64 + mt * 16 + quad * 4 + r;
            float bi = b2[row];
#pragma unroll
            for (int nt = 0; nt < 4; ++nt) {
                int cc = s0 + wn * 64 + nt * 16 + l15;
                out[(size_t)bz * 4194304 + (size_t)row * S_DIM + cc] = acc[mt][nt][r] + bi;
            }
        }
}

extern "C" void kernel_launch(void* const* d_in, const int* in_sizes, int n_in,
                              void* d_out, int out_size, void* d_ws, size_t ws_size,
                              hipStream_t stream) {
    const float* feat   = (const float*)d_in[0];
    const float* coarse = (const float*)d_in[1];
    const float* w1     = (const float*)d_in[2];
    const float* gamma  = (const float*)d_in[3];
    const float* beta   = (const float*)d_in[4];
    const float* mean   = (const float*)d_in[5];
    const float* var    = (const float*)d_in[6];
    const float* w2     = (const float*)d_in[7];
    const float* b2     = (const float*)d_in[8];
    float* out = (float*)d_out;

    char* base = (char*)d_ws;  // ~204 MB
    u16* qhi   = (u16*)(base);                   // [4][256][16384]
    u16* qlo   = (u16*)(base + 33554432);
    u16* khi   = (u16*)(base + 67108864);        // [4][256][16384]
    u16* klo   = (u16*)(base + 100663296);
    float* Ep  = (float*)(base + 134217728);     // [32][4][256][256] = 33.5 MB
    float* att = (float*)(base + 201326592);     // [4][256][256]
    u16* M2h   = (u16*)(base + 202375168);
    u16* w1hi  = (u16*)(base + 202899456);
    u16* w1lo  = (u16*)(base + 203161600);
    float* b1  = (float*)(base + 203423744);

    prep_kernel<<<4112, 256, 0, stream>>>(coarse, w1, gamma, beta, mean, var,
                                          qhi, qlo, w1hi, w1lo, b1);

    conv_kernel<<<dim3(128, 2, 4), 256, 0, stream>>>(w1hi, w1lo, feat, b1, khi, klo);

    energy_kernel<<<dim3(32, 4, 4), 256, 0, stream>>>(qhi, qlo, khi, klo, Ep);

    softmax_kernel<<<1024, 256, 0, stream>>>(Ep, att);

    m2h_kernel<<<1024, 256, 0, stream>>>(w2, att, M2h);

    final_kernel<<<dim3(128, 2, 4), 256, 0, stream>>>(M2h, coarse, b2, out);
}

// Round 4
// 422.246 us; speedup vs baseline: 1.0905x; 1.0020x over previous
//
#include <hip/hip_runtime.h>

// N=4, Cin=512, C=D=256, S=H*W=16384
// All low precision is FP16 (11-bit mantissa):
// prep   : split coarse -> q hi/lo fp16 | fold BN into w1 -> fp16 hi/lo
// conv   : k = relu(BN(conv1)) NT-MFMA 2-pass (A=w1 hi/lo pair, B=feat single fp16).
// energy : E_part[32 splits] = q.k^T NT-MFMA 3-pass fp16 (drop ql*kl), partial stores
// softmax: att = softmax(-sum Ep) over c  (max-shift cancels)
// m2h    : M2[o,d] = w2 @ att^T -> fp16
// final  : out = M2 @ q + b2; A=M2h fp16 single, B=coarse fp32 -> single fp16 cvt
//
// PIPELINE (this round): counted-vmcnt double-buffer (T4).  Round-3's
// __syncthreads() drained vmcnt to 0 = waited for the JUST-ISSUED prefetch
// (drain-0 == no pipeline, m218).  Now: stage(t+1); s_waitcnt vmcnt(L);
// s_barrier; compute(t); s_barrier — the wait covers stage(t), issued one
// full iteration earlier, so HBM latency is hidden at depth 2.
// L = loads/wave/iter: conv,energy = 8; final = 6.  sched_barrier(0) fences
// around compute per rule #18/m152 (raw s_barrier does not order ds ops).
//
// LDS layouts (unchanged):
//   fp16 tiles: [row 128][32 k] u16, octet-XOR stored[row][s]=logical[row][s^((row>>1)&3)]
//     staging source = 64B-coalesced row chunks; frag ds_read_b128 2-way banks (free).
//   B fp32 tile: [32][128] linear, col ^= ((k_oct&1)<<4) on global source and read.

#define S_DIM 16384
#define C_DIM 256
#define CIN 512

typedef unsigned short u16;
typedef _Float16 f16;
typedef __attribute__((ext_vector_type(8))) _Float16 f16x8;
typedef __attribute__((ext_vector_type(4))) float f32x4;

__device__ __forceinline__ u16 f2h(float x) {
    f16 h = (f16)x;  // v_cvt_f16_f32, RNE
    return *(u16*)&h;
}
__device__ __forceinline__ float h2f(u16 u) {
    f16 h = *(f16*)&u;
    return (float)h;
}
__device__ __forceinline__ void gld16(const u16* g, u16* l) {
    __builtin_amdgcn_global_load_lds((const __attribute__((address_space(1))) void*)g,
                                     (__attribute__((address_space(3))) void*)l, 16, 0, 0);
}
__device__ __forceinline__ void gld16f(const float* g, float* l) {
    __builtin_amdgcn_global_load_lds((const __attribute__((address_space(1))) void*)g,
                                     (__attribute__((address_space(3))) void*)l, 16, 0, 0);
}

// stage one [128 rows][32 k] u16 tile chunk pair (rows wave*32.. & +16) into LDS
__device__ __forceinline__ void stage_pair(const u16* g, int kb, size_t row16,
                                           u16* d, int wave) {
    gld16(g + kb, d + wave * 1024);
    gld16(g + kb + row16, d + wave * 1024 + 512);
}
// stage [32 k][128 s] fp32 tile (wave stages k rows 8w..8w+7)
__device__ __forceinline__ void stage_b(const float* g, int kb, float* d, int wave) {
#pragma unroll
    for (int p = 0; p < 4; ++p)
        gld16f(g + (size_t)(kb + 2 * p) * S_DIM, d + wave * 1024 + p * 256);
}

// ================= prep: split coarse -> q hi/lo fp16 | fold w1 =================
__global__ __launch_bounds__(256) void prep_kernel(
    const float* __restrict__ coarse, const float* __restrict__ w1,
    const float* __restrict__ gamma, const float* __restrict__ beta,
    const float* __restrict__ mean, const float* __restrict__ var,
    u16* __restrict__ qhi, u16* __restrict__ qlo,
    u16* __restrict__ w1hi, u16* __restrict__ w1lo, float* __restrict__ b1) {
    int b = blockIdx.x;
    int t = threadIdx.x;
    if (b < 4096) {
        size_t i = (size_t)b * 256 + t;
        for (size_t c = i; c < 4194304u; c += 1048576u) {
            float4 v = ((const float4*)coarse)[c];
            float vv[4] = {v.x, v.y, v.z, v.w};
            u16 h[4], l[4];
#pragma unroll
            for (int j = 0; j < 4; ++j) {
                h[j] = f2h(vv[j]);
                l[j] = f2h(vv[j] - h2f(h[j]));
            }
            *(uint2*)&qhi[c * 4] = *(uint2*)h;
            *(uint2*)&qlo[c * 4] = *(uint2*)l;
        }
    } else {
        int o = (b - 4096) * 16 + (t >> 4);
        int lane16 = t & 15;
        float sc = gamma[o] * rsqrtf(var[o] + 1e-5f);
        for (int i = lane16; i < CIN; i += 16) {
            float v = w1[o * CIN + i] * sc;
            u16 h = f2h(v);
            w1hi[o * CIN + i] = h;
            w1lo[o * CIN + i] = f2h(v - h2f(h));
        }
        if (lane16 == 0) b1[o] = beta[o] - mean[o] * sc;
    }
}

// ====== conv: k = relu(BN(w1 @ feat)), 2-pass fp16, counted-vmcnt dbuf ==========
__global__ __launch_bounds__(256) void conv_kernel(
    const u16* __restrict__ w1hi, const u16* __restrict__ w1lo,
    const float* __restrict__ feat, const float* __restrict__ b1,
    u16* __restrict__ khi, u16* __restrict__ klo) {
    __shared__ u16 AhS[2][4096], AlS[2][4096];
    __shared__ float BfS[2][4096];
    int s0 = blockIdx.x * 128;
    int m0 = blockIdx.y * 128;
    int bz = blockIdx.z;
    int tid = threadIdx.x, wave = tid >> 6, lane = tid & 63;
    int quad = lane >> 4, l15 = lane & 15;
    int wm = wave >> 1, wn = wave & 1;

    int Lr = lane >> 2, Ls = lane & 3;
    int koff = (Ls ^ ((Lr >> 1) & 3)) * 8;  // octet-XOR on source (dest stays linear)
    const u16* gAh = w1hi + (size_t)(m0 + wave * 32 + Lr) * CIN + koff;
    const u16* gAl = w1lo + (size_t)(m0 + wave * 32 + Lr) * CIN + koff;
    int bcol = ((lane & 31) * 4) ^ ((wave & 1) << 4);
    const float* gB = feat + (size_t)bz * ((size_t)CIN * S_DIM)
                    + (size_t)(8 * wave + (lane >> 5)) * S_DIM + s0 + bcol;

    f32x4 zero = {0.f, 0.f, 0.f, 0.f};
    f32x4 acc[4][4];
#pragma unroll
    for (int i = 0; i < 4; ++i)
#pragma unroll
        for (int j = 0; j < 4; ++j) acc[i][j] = zero;

    stage_pair(gAh, 0, 16 * CIN, AhS[0], wave);
    stage_pair(gAl, 0, 16 * CIN, AlS[0], wave);
    stage_b(gB, 0, BfS[0], wave);

    int cur = 0;
    for (int kb = 0; kb < CIN; kb += 32) {
        if (kb + 32 < CIN) {
            stage_pair(gAh, kb + 32, 16 * CIN, AhS[cur ^ 1], wave);
            stage_pair(gAl, kb + 32, 16 * CIN, AlS[cur ^ 1], wave);
            stage_b(gB, kb + 32, BfS[cur ^ 1], wave);
            asm volatile("s_waitcnt vmcnt(8)" ::: "memory");  // stage(t) done (mine)
        } else {
            asm volatile("s_waitcnt vmcnt(0)" ::: "memory");
        }
        __builtin_amdgcn_s_barrier();         // everyone's stage(t) done
        __builtin_amdgcn_sched_barrier(0);    // no ds_read hoists above this

        f16x8 a_h[4], a_l[4];
        int axor = ((l15 >> 1) & 3);  // (row>>1)&3 for row = wm*64+t*16+l15
        int ao = (wm * 64 + l15) * 32 + ((quad ^ axor) * 8);
#pragma unroll
        for (int t = 0; t < 4; ++t) {
            a_h[t] = *(const f16x8*)&AhS[cur][ao + t * 512];
            a_l[t] = *(const f16x8*)&AlS[cur][ao + t * 512];
        }
        f16x8 b_s[4];
        int fl = (quad & 1) << 4;
        const float* Brow = BfS[cur] + quad * 1024;  // k rows quad*8..quad*8+7
#pragma unroll
        for (int nt = 0; nt < 4; ++nt) {
            int nf = (wn * 64 + nt * 16 + l15) ^ fl;
            union { u16 u[8]; f16x8 v; } T;
#pragma unroll
            for (int j = 0; j < 8; ++j) T.u[j] = f2h(Brow[j * 128 + nf]);
            b_s[nt] = T.v;
        }
#pragma unroll
        for (int mt = 0; mt < 4; ++mt)
#pragma unroll
            for (int nt = 0; nt < 4; ++nt) {
                acc[mt][nt] = __builtin_amdgcn_mfma_f32_16x16x32_f16(a_h[mt], b_s[nt], acc[mt][nt], 0, 0, 0);
                acc[mt][nt] = __builtin_amdgcn_mfma_f32_16x16x32_f16(a_l[mt], b_s[nt], acc[mt][nt], 0, 0, 0);
            }
        __builtin_amdgcn_sched_barrier(0);    // no compute sinks below this
        __builtin_amdgcn_s_barrier();         // reads of buf done before overwrite
        cur ^= 1;
    }

#pragma unroll
    for (int mt = 0; mt < 4; ++mt) {
#pragma unroll
        for (int r = 0; r < 4; ++r) {
            int row = m0 + wm * 64 + mt * 16 + quad * 4 + r;
            float bi = b1[row];
#pragma unroll
            for (int nt = 0; nt < 4; ++nt) {
                int cc = s0 + wn * 64 + nt * 16 + l15;
                float v = fmaxf(acc[mt][nt][r] + bi, 0.f);
                u16 h = f2h(v);
                size_t o = (size_t)bz * 4194304 + (size_t)row * S_DIM + cc;
                khi[o] = h;
                klo[o] = f2h(v - h2f(h));
            }
        }
    }
}

// === energy: Ep[split] = q.k^T (3-pass fp16), 32 splits, counted-vmcnt dbuf =====
__global__ __launch_bounds__(256) void energy_kernel(
    const u16* __restrict__ qhi, const u16* __restrict__ qlo,
    const u16* __restrict__ khi, const u16* __restrict__ klo,
    float* __restrict__ Ep) {
    __shared__ u16 AhS[2][4096], BhS[2][4096], AlS[2][4096], BlS[2][4096];
    int kBeg = blockIdx.x * 512;
    int m0 = (blockIdx.y >> 1) * 128;
    int n0 = (blockIdx.y & 1) * 128;
    int bz = blockIdx.z;
    int tid = threadIdx.x, wave = tid >> 6, lane = tid & 63;
    int quad = lane >> 4, l15 = lane & 15;
    int wm = wave >> 1, wn = wave & 1;

    int Lr = lane >> 2, Ls = lane & 3;
    int koff = (Ls ^ ((Lr >> 1) & 3)) * 8;
    size_t bo = (size_t)bz * 4194304;
    const u16* gAh = qhi + bo + (size_t)(m0 + wave * 32 + Lr) * S_DIM + kBeg + koff;
    const u16* gAl = qlo + bo + (size_t)(m0 + wave * 32 + Lr) * S_DIM + kBeg + koff;
    const u16* gBh = khi + bo + (size_t)(n0 + wave * 32 + Lr) * S_DIM + kBeg + koff;
    const u16* gBl = klo + bo + (size_t)(n0 + wave * 32 + Lr) * S_DIM + kBeg + koff;

    f32x4 zero = {0.f, 0.f, 0.f, 0.f};
    f32x4 acc[4][4];
#pragma unroll
    for (int i = 0; i < 4; ++i)
#pragma unroll
        for (int j = 0; j < 4; ++j) acc[i][j] = zero;

    const size_t row16 = (size_t)16 * S_DIM;
    stage_pair(gAh, 0, row16, AhS[0], wave);
    stage_pair(gBh, 0, row16, BhS[0], wave);
    stage_pair(gAl, 0, row16, AlS[0], wave);
    stage_pair(gBl, 0, row16, BlS[0], wave);

    int cur = 0;
    for (int kb = 0; kb < 512; kb += 32) {
        if (kb + 32 < 512) {
            stage_pair(gAh, kb + 32, row16, AhS[cur ^ 1], wave);
            stage_pair(gBh, kb + 32, row16, BhS[cur ^ 1], wave);
            stage_pair(gAl, kb + 32, row16, AlS[cur ^ 1], wave);
            stage_pair(gBl, kb + 32, row16, BlS[cur ^ 1], wave);
            asm volatile("s_waitcnt vmcnt(8)" ::: "memory");
        } else {
            asm volatile("s_waitcnt vmcnt(0)" ::: "memory");
        }
        __builtin_amdgcn_s_barrier();
        __builtin_amdgcn_sched_barrier(0);

        f16x8 a_h[4], b_h[4], a_l[4], b_l[4];
        int axor = ((l15 >> 1) & 3);
        int aOff = (wm * 64 + l15) * 32 + ((quad ^ axor) * 8);
        int bOff = (wn * 64 + l15) * 32 + ((quad ^ axor) * 8);
#pragma unroll
        for (int t = 0; t < 4; ++t) {
            a_h[t] = *(const f16x8*)&AhS[cur][aOff + t * 512];
            b_h[t] = *(const f16x8*)&BhS[cur][bOff + t * 512];
            a_l[t] = *(const f16x8*)&AlS[cur][aOff + t * 512];
            b_l[t] = *(const f16x8*)&BlS[cur][bOff + t * 512];
        }
#pragma unroll
        for (int mt = 0; mt < 4; ++mt)
#pragma unroll
            for (int nt = 0; nt < 4; ++nt) {
                acc[mt][nt] = __builtin_amdgcn_mfma_f32_16x16x32_f16(a_h[mt], b_h[nt], acc[mt][nt], 0, 0, 0);
                acc[mt][nt] = __builtin_amdgcn_mfma_f32_16x16x32_f16(a_h[mt], b_l[nt], acc[mt][nt], 0, 0, 0);
                acc[mt][nt] = __builtin_amdgcn_mfma_f32_16x16x32_f16(a_l[mt], b_h[nt], acc[mt][nt], 0, 0, 0);
            }
        __builtin_amdgcn_sched_barrier(0);
        __builtin_amdgcn_s_barrier();
        cur ^= 1;
    }

    float* Ce = Ep + ((size_t)(blockIdx.x * 4 + bz)) * 65536;
#pragma unroll
    for (int mt = 0; mt < 4; ++mt)
#pragma unroll
        for (int r = 0; r < 4; ++r) {
            int row = m0 + wm * 64 + mt * 16 + quad * 4 + r;
#pragma unroll
            for (int nt = 0; nt < 4; ++nt) {
                int cc = n0 + wn * 64 + nt * 16 + l15;
                Ce[(size_t)row * C_DIM + cc] = acc[mt][nt][r];
            }
        }
}

// ================= softmax(-sum Ep) over c =================
__global__ __launch_bounds__(256) void softmax_kernel(const float* __restrict__ Ep,
                                                      float* __restrict__ att) {
    __shared__ float red[4], red2[4];
    int b = blockIdx.x;  // n*256+d
    int t = threadIdx.x;
    const float* p = Ep + (size_t)b * 256 + t;
    float v = 0.f;
#pragma unroll 8
    for (int s = 0; s < 32; ++s) v += p[(size_t)s * 262144];
    float m = v;
#pragma unroll
    for (int o = 32; o > 0; o >>= 1) m = fminf(m, __shfl_xor(m, o, 64));
    int lane = t & 63, wid = t >> 6;
    if (lane == 0) red[wid] = m;
    __syncthreads();
    m = fminf(fminf(red[0], red[1]), fminf(red[2], red[3]));
    float e = expf(m - v);
    float s = e;
#pragma unroll
    for (int o = 32; o > 0; o >>= 1) s += __shfl_xor(s, o, 64);
    if (lane == 0) red2[wid] = s;
    __syncthreads();
    s = red2[0] + red2[1] + red2[2] + red2[3];
    att[(size_t)b * 256 + t] = e / s;
}

// ================= M2h[n,o,d] = fp16( sum_c w2[o,c]*att[n,d,c] ) =================
__global__ __launch_bounds__(256) void m2h_kernel(const float* __restrict__ w2,
                                                  const float* __restrict__ att,
                                                  u16* __restrict__ M2h) {
    int t = blockIdx.x * 256 + threadIdx.x;
    int d = t & 255, o = (t >> 8) & 255, n = t >> 16;
    const float4* wr = (const float4*)(w2 + (size_t)o * C_DIM);
    const float4* ar = (const float4*)(att + ((size_t)n * C_DIM + d) * C_DIM);
    float s = 0.0f;
#pragma unroll 4
    for (int c4 = 0; c4 < 64; ++c4) {
        float4 w = wr[c4];
        float4 a = ar[c4];
        s += w.x * a.x + w.y * a.y + w.z * a.z + w.w * a.w;
    }
    M2h[((size_t)n * C_DIM + o) * C_DIM + d] = f2h(s);
}

// ========= final: out = M2 @ q + b2 (1-pass fp16, counted-vmcnt dbuf) ===========
__global__ __launch_bounds__(256) void final_kernel(
    const u16* __restrict__ M2h, const float* __restrict__ coarse,
    const float* __restrict__ b2, float* __restrict__ out) {
    __shared__ u16 AhS[2][4096];
    __shared__ float BfS[2][4096];
    int s0 = blockIdx.x * 128;
    int m0 = blockIdx.y * 128;
    int bz = blockIdx.z;
    int tid = threadIdx.x, wave = tid >> 6, lane = tid & 63;
    int quad = lane >> 4, l15 = lane & 15;
    int wm = wave >> 1, wn = wave & 1;

    int Lr = lane >> 2, Ls = lane & 3;
    int koff = (Ls ^ ((Lr >> 1) & 3)) * 8;
    const u16* gA = M2h + (size_t)bz * 65536 + (size_t)(m0 + wave * 32 + Lr) * C_DIM + koff;
    int bcol = ((lane & 31) * 4) ^ ((wave & 1) << 4);
    const float* gB = coarse + (size_t)bz * 4194304
                    + (size_t)(8 * wave + (lane >> 5)) * S_DIM + s0 + bcol;

    f32x4 zero = {0.f, 0.f, 0.f, 0.f};
    f32x4 acc[4][4];
#pragma unroll
    for (int i = 0; i < 4; ++i)
#pragma unroll
        for (int j = 0; j < 4; ++j) acc[i][j] = zero;

    stage_pair(gA, 0, 16 * C_DIM, AhS[0], wave);
    stage_b(gB, 0, BfS[0], wave);

    int cur = 0;
    for (int kb = 0; kb < C_DIM; kb += 32) {
        if (kb + 32 < C_DIM) {
            stage_pair(gA, kb + 32, 16 * C_DIM, AhS[cur ^ 1], wave);
            stage_b(gB, kb + 32, BfS[cur ^ 1], wave);
            asm volatile("s_waitcnt vmcnt(6)" ::: "memory");
        } else {
            asm volatile("s_waitcnt vmcnt(0)" ::: "memory");
        }
        __builtin_amdgcn_s_barrier();
        __builtin_amdgcn_sched_barrier(0);

        f16x8 a_s[4];
        int axor = ((l15 >> 1) & 3);
        int ao = (wm * 64 + l15) * 32 + ((quad ^ axor) * 8);
#pragma unroll
        for (int t = 0; t < 4; ++t) a_s[t] = *(const f16x8*)&AhS[cur][ao + t * 512];
        f16x8 b_s[4];
        int fl = (quad & 1) << 4;
        const float* Brow = BfS[cur] + quad * 1024;
#pragma unroll
        for (int nt = 0; nt < 4; ++nt) {
            int nf = (wn * 64 + nt * 16 + l15) ^ fl;
            union { u16 u[8]; f16x8 v; } T;
#pragma unroll
            for (int j = 0; j < 8; ++j) T.u[j] = f2h(Brow[j * 128 + nf]);
            b_s[nt] = T.v;
        }
#pragma unroll
        for (int mt = 0; mt < 4; ++mt)
#pragma unroll
            for (int nt = 0; nt < 4; ++nt)
                acc[mt][nt] = __builtin_amdgcn_mfma_f32_16x16x32_f16(a_s[mt], b_s[nt], acc[mt][nt], 0, 0, 0);
        __builtin_amdgcn_sched_barrier(0);
        __builtin_amdgcn_s_barrier();
        cur ^= 1;
    }

#pragma unroll
    for (int mt = 0; mt < 4; ++mt)
#pragma unroll
        for (int r = 0; r < 4; ++r) {
            int row = m0 + wm * 64 + mt * 16 + quad * 4 + r;
            float bi = b2[row];
#pragma unroll
            for (int nt = 0; nt < 4; ++nt) {
                int cc = s0 + wn * 64 + nt * 16 + l15;
                out[(size_t)bz * 4194304 + (size_t)row * S_DIM + cc] = acc[mt][nt][r] + bi;
            }
        }
}

extern "C" void kernel_launch(void* const* d_in, const int* in_sizes, int n_in,
                              void* d_out, int out_size, void* d_ws, size_t ws_size,
                              hipStream_t stream) {
    const float* feat   = (const float*)d_in[0];
    const float* coarse = (const float*)d_in[1];
    const float* w1     = (const float*)d_in[2];
    const float* gamma  = (const float*)d_in[3];
    const float* beta   = (const float*)d_in[4];
    const float* mean   = (const float*)d_in[5];
    const float* var    = (const float*)d_in[6];
    const float* w2     = (const float*)d_in[7];
    const float* b2     = (const float*)d_in[8];
    float* out = (float*)d_out;

    char* base = (char*)d_ws;  // ~204 MB
    u16* qhi   = (u16*)(base);                   // [4][256][16384]
    u16* qlo   = (u16*)(base + 33554432);
    u16* khi   = (u16*)(base + 67108864);        // [4][256][16384]
    u16* klo   = (u16*)(base + 100663296);
    float* Ep  = (float*)(base + 134217728);     // [32][4][256][256] = 33.5 MB
    float* att = (float*)(base + 201326592);     // [4][256][256]
    u16* M2h   = (u16*)(base + 202375168);
    u16* w1hi  = (u16*)(base + 202899456);
    u16* w1lo  = (u16*)(base + 203161600);
    float* b1  = (float*)(base + 203423744);

    prep_kernel<<<4112, 256, 0, stream>>>(coarse, w1, gamma, beta, mean, var,
                                          qhi, qlo, w1hi, w1lo, b1);

    conv_kernel<<<dim3(128, 2, 4), 256, 0, stream>>>(w1hi, w1lo, feat, b1, khi, klo);

    energy_kernel<<<dim3(32, 4, 4), 256, 0, stream>>>(qhi, qlo, khi, klo, Ep);

    softmax_kernel<<<1024, 256, 0, stream>>>(Ep, att);

    m2h_kernel<<<1024, 256, 0, stream>>>(w2, att, M2h);

    final_kernel<<<dim3(128, 2, 4), 256, 0, stream>>>(M2h, coarse, b2, out);
}